// Round 15
// baseline (48.490 us; speedup 1.0000x reference)
//
#include <hip/hip_runtime.h>
#include <hip/hip_bf16.h>

// ConditionalDense: out[b,u] = sum_d x[b,d]*kernel[cls[b],d,u] + bias[cls[b],u]
// B=2048, D=512, U=512, C=100, all float32.
// R15 = R14 (S=32 MFMA, ring W staging, bf16 xsb) retiled for 3 blk/CU
// coverage: TU 128->64 (8 ytiles, ~808 blocks), 4 KB W pieces ring-4,
// LDS 48.4 KB. Mechanism: per-step compute+barrier bubble (~650 cy) sits
// on the DMA cadence; 2 blk/CU covered ~70% of it (R14 at 68-76% HBM),
// 3 blk/CU should cover ~100% -> HBM-paced.

typedef __attribute__((ext_vector_type(8))) short bf16x8;
typedef __attribute__((ext_vector_type(4))) short short4v;
typedef __attribute__((ext_vector_type(4))) float floatx4;

constexpr int C_CLS   = 100;
constexpr int B_N     = 2048;
constexpr int D_DIM   = 512;
constexpr int U_DIM   = 512;
constexpr int S_CHUNK = 32;     // samples per chunk = 2 MFMA m-tiles
constexpr int MAX_CHUNKS = 164; // >= worst case (2048+100*31)/32 = 161
constexpr int TU      = 64;     // u-columns per block (wave owns 16)
constexpr int PROWS   = 16;     // d-rows per staged W piece (4 KB)
constexpr int PIECES  = D_DIM / PROWS;   // 32
constexpr int NQ      = 4;      // W ring depth
constexpr int NWG     = 8 * MAX_CHUNKS;  // 1312 = 8*164

__device__ __forceinline__ short f2bf(float f) {
    return (short)__builtin_bit_cast(unsigned short, __float2bfloat16(f));
}

// ---------------- fused sort kernel (single block, 1024 threads) ----------------

__global__ void k_sort(const int* __restrict__ cls, int* __restrict__ order,
                       int* __restrict__ total_chunks, int* __restrict__ chunk_cls,
                       int* __restrict__ chunk_start, int* __restrict__ chunk_len) {
    __shared__ int s_cnt[128], s_off[128], s_chk[128], s_cur[128], s_base[128];
    int tid = threadIdx.x;
    if (tid < 128) s_cnt[tid] = 0;
    __syncthreads();
    for (int i = tid; i < B_N; i += 1024) atomicAdd(&s_cnt[cls[i]], 1);
    __syncthreads();
    int cnt = 0, nch = 0;
    if (tid < 128) {
        cnt = (tid < C_CLS) ? s_cnt[tid] : 0;
        nch = (cnt + S_CHUNK - 1) / S_CHUNK;
        s_off[tid] = cnt; s_chk[tid] = nch;
    }
    __syncthreads();
    for (int st = 1; st < 128; st <<= 1) {   // Hillis-Steele inclusive scan
        int a = 0, b = 0;
        if (tid >= st && tid < 128) { a = s_off[tid - st]; b = s_chk[tid - st]; }
        __syncthreads();
        if (tid < 128) { s_off[tid] += a; s_chk[tid] += b; }
        __syncthreads();
    }
    if (tid < C_CLS) {
        int off = s_off[tid] - cnt;   // exclusive prefix of counts
        int cb  = s_chk[tid] - nch;   // exclusive prefix of chunk counts
        s_base[tid] = off;
        s_cur[tid]  = 0;
        for (int j = 0; j < nch; ++j) {
            chunk_cls[cb + j]   = tid;
            chunk_start[cb + j] = off + j * S_CHUNK;
            chunk_len[cb + j]   = min(S_CHUNK, cnt - j * S_CHUNK);
        }
    }
    if (tid == 127) *total_chunks = s_chk[127];
    __syncthreads();
    for (int i = tid; i < B_N; i += 1024) {
        int c = cls[i];
        int p = atomicAdd(&s_cur[c], 1);
        order[s_base[c] + p] = i;
    }
}

// ---------------- main kernel ----------------
// Block = (chunk, ytile): 32 samples x 64 u x full D=512. 256 thr / 4 waves.
// Wave wv computes u-cols [wv*16, wv*16+16) (1 n-tile) x 2 m-tiles.
// W piece = 16 rows x 64 f32 = 4 KB, ring-4, LINEAR layout; DMA = 1 instr
// per wave per piece (wave wv stages rows 4wv..4wv+3: lane l -> row
// 4wv+(l>>4), 16-B col chunk l&15). xsb keeps R14's swizzled bf16 layout.

#define ISSUE(pi, qq) do {                                                    \
    const int db_ = (pi) * PROWS + 4 * wv;                                    \
    const float* gp_ = Wg + (size_t)(db_ + (lane >> 4)) * U_DIM               \
                       + ((lane & 15) << 2);                                  \
    __builtin_amdgcn_global_load_lds(                                         \
        (const __attribute__((address_space(1))) void*)gp_,                   \
        (__attribute__((address_space(3))) void*)&wbuf[qq][4 * wv][0],        \
        16, 0, 0);                                                            \
} while (0)

#define COMPUTE(pi, qq) do {                                                  \
    bf16x8 a8_0, a8_1;                                                        \
    {                                                                         \
        const int xb_ = ((pi) * 32 + g4 * 8) ^ sxw_;                          \
        short4v a4 = *reinterpret_cast<const short4v*>(                       \
            (const char*)xsb + sA * 1024 + xb_);                              \
        a8_0[0]=a4[0]; a8_0[1]=a4[1]; a8_0[2]=a4[2]; a8_0[3]=a4[3];           \
        a8_0[4]=a4[0]; a8_0[5]=a4[1]; a8_0[6]=a4[2]; a8_0[7]=a4[3];           \
        short4v a4b = *reinterpret_cast<const short4v*>(                      \
            (const char*)xsb + (16 + sA) * 1024 + xb_);                       \
        a8_1[0]=a4b[0]; a8_1[1]=a4b[1]; a8_1[2]=a4b[2]; a8_1[3]=a4b[3];       \
        a8_1[4]=a4b[0]; a8_1[5]=a4b[1]; a8_1[6]=a4b[2]; a8_1[7]=a4b[3];       \
    }                                                                         \
    const char* wb_ = (const char*)wbuf + (qq) * (PROWS * TU * 4);            \
    {                                                                         \
        const int cb4_ = (wv * 16 + sA) << 2;   /* byte col in 256-B row */   \
        bf16x8 b8;                                                            \
        _Pragma("unroll")                                                     \
        for (int j_ = 0; j_ < 4; ++j_) {                                      \
            const int rl_ = g4 * 4 + j_;                                      \
            float w_ = *reinterpret_cast<const float*>(wb_ + rl_ * 256 + cb4_); \
            b8[j_] = f2bf(w_);                                                \
        }                                                                     \
        b8[4] = 0; b8[5] = 0; b8[6] = 0; b8[7] = 0;                           \
        acc0 = __builtin_amdgcn_mfma_f32_16x16x32_bf16(a8_0, b8, acc0, 0, 0, 0); \
        acc1 = __builtin_amdgcn_mfma_f32_16x16x32_bf16(a8_1, b8, acc1, 0, 0, 0); \
    }                                                                         \
} while (0)

#define STEP(pi, NCNT) do {                                                   \
    asm volatile("s_waitcnt vmcnt(" #NCNT ")" ::: "memory");                  \
    __builtin_amdgcn_s_barrier();          /* piece pi fully in LDS */        \
    COMPUTE(pi, (pi) & 3);                                                    \
    asm volatile("" ::: "memory");                                            \
    __builtin_amdgcn_s_barrier();          /* all waves done with slot */     \
    if ((pi) + NQ < PIECES) ISSUE((pi) + NQ, (pi) & 3);                       \
} while (0)

__launch_bounds__(256, 3)
__global__ void k_main(const float* __restrict__ x, const float* __restrict__ kern,
                       const float* __restrict__ bias, const int* __restrict__ order,
                       const int* __restrict__ total_chunks,
                       const int* __restrict__ chunk_cls,
                       const int* __restrict__ chunk_start,
                       const int* __restrict__ chunk_len,
                       float* __restrict__ out) {
    // Runtime-balanced bijective XCD swizzle over active count A = 8*tc.
    // One chunk's 8 ytiles are g-adjacent -> one XCD (x + W L2 locality).
    int tc = *total_chunks;
    int A  = 8 * tc;
    int xc = blockIdx.x & 7;
    int ii = blockIdx.x >> 3;
    int q  = A >> 3, r = A & 7;
    int mycnt = (xc < r) ? (q + 1) : q;
    if (ii >= mycnt) return;            // block-uniform exit (before barriers)
    int g = ((xc < r) ? xc * (q + 1) : r * (q + 1) + (xc - r) * q) + ii;

    int chunk = g >> 3;
    int ytile = g & 7;

    int tid  = threadIdx.x;
    int lane = tid & 63;
    int wv   = tid >> 6;
    int sA   = lane & 15;
    int g4   = lane >> 4;
    const int sxw_ = (sA & 7) << 4;     // xsb row-XOR (rows sA and 16+sA share it)

    int c     = chunk_cls[chunk];
    int start = chunk_start[chunk];
    int len   = chunk_len[chunk];
    int u0    = ytile * TU;

    __shared__ float          wbuf[NQ][PROWS][TU];  // 16 KB, ring-4, linear
    __shared__ unsigned short xsb[S_CHUNK][D_DIM];  // 32 KB bf16, swizzled
    __shared__ int            sidx[S_CHUNK];        // -> 48.4 KB, 3 blk/CU

    const float* Wg = kern + (size_t)c * (D_DIM * U_DIM) + u0;

    // ---- prologue ----
    if (tid < S_CHUNK) sidx[tid] = (tid < len) ? order[start + tid] : -1;
    asm volatile("s_waitcnt lgkmcnt(0)" ::: "memory");
    __builtin_amdgcn_s_barrier();          // sidx visible

    // x staging in 2 passes of 8 float4 (32 VGPR live) to fit 3-wave/EU cap.
    int srow = tid >> 4;                   // 0..15
    int cb   = (tid & 15) * 32;            // f32 col base
    ISSUE(0, 0);                           // W pieces 0..3 (1 instr/wave each)
    ISSUE(1, 1);
    ISSUE(2, 2);
    ISSUE(3, 3);
    #pragma unroll
    for (int p = 0; p < 2; ++p) {
        int row = p * 16 + srow;
        int b0 = sidx[row]; if (b0 < 0) b0 = sidx[0];   // pad: junk, never stored
        float4 xv[8];
        #pragma unroll
        for (int j = 0; j < 8; ++j)
            xv[j] = reinterpret_cast<const float4*>(x + (size_t)b0 * D_DIM + cb)[j];
        asm volatile("s_waitcnt vmcnt(4)" ::: "memory");   // my 8 x-loads done; W's 4 fly
        char* xrow = (char*)xsb + row * 1024;
        int   swz  = (row & 7) << 4;
        #pragma unroll
        for (int m = 0; m < 4; ++m) {
            bf16x8 pk;
            pk[0] = f2bf(xv[2*m].x);   pk[1] = f2bf(xv[2*m].y);
            pk[2] = f2bf(xv[2*m].z);   pk[3] = f2bf(xv[2*m].w);
            pk[4] = f2bf(xv[2*m+1].x); pk[5] = f2bf(xv[2*m+1].y);
            pk[6] = f2bf(xv[2*m+1].z); pk[7] = f2bf(xv[2*m+1].w);
            *reinterpret_cast<bf16x8*>(xrow + ((cb * 2 + m * 16) ^ swz)) = pk;
        }
    }
    asm volatile("s_waitcnt lgkmcnt(0)" ::: "memory");
    __builtin_amdgcn_s_barrier();          // xsb visible; pipeline primed

    floatx4 acc0 = (floatx4){0.f, 0.f, 0.f, 0.f};
    floatx4 acc1 = (floatx4){0.f, 0.f, 0.f, 0.f};

    // ---- main loop: 32 pieces, ring-4, steady vmcnt(3) = 3 pieces in flight ----
    #pragma unroll 1
    for (int i = 0; i <= 28; ++i) STEP(i, 3);
    STEP(29, 2);
    STEP(30, 1);
    STEP(31, 0);

    // ---- epilogue: direct stores, one writer per output element ----
    {
        int u  = u0 + wv * 16 + sA;
        float bb = bias[c * U_DIM + u];
        #pragma unroll
        for (int r2 = 0; r2 < 4; ++r2) {
            int b0 = sidx[g4 * 4 + r2];
            if (b0 >= 0) out[(size_t)b0 * U_DIM + u] = acc0[r2] + bb;
            int b1 = sidx[16 + g4 * 4 + r2];
            if (b1 >= 0) out[(size_t)b1 * U_DIM + u] = acc1[r2] + bb;
        }
    }
}

// ---------------- launch ----------------

extern "C" void kernel_launch(void* const* d_in, const int* in_sizes, int n_in,
                              void* d_out, int out_size, void* d_ws, size_t ws_size,
                              hipStream_t stream) {
    const float* x    = (const float*)d_in[0];
    const int*   cls  = (const int*)d_in[1];
    const float* kern = (const float*)d_in[2];
    const float* bias = (const float*)d_in[3];
    float*       out  = (float*)d_out;

    int* ws           = (int*)d_ws;
    int* order        = ws;          // 2048
    int* total_chunks = ws + 2048;   // 1
    int* chunk_cls    = ws + 2112;   // 164
    int* chunk_start  = ws + 2304;   // 164
    int* chunk_len    = ws + 2496;   // 164

    hipLaunchKernelGGL(k_sort, dim3(1), dim3(1024), 0, stream,
                       cls, order, total_chunks, chunk_cls, chunk_start, chunk_len);
    hipLaunchKernelGGL(k_main, dim3(NWG), dim3(256), 0, stream,
                       x, kern, bias, order, total_chunks, chunk_cls, chunk_start, chunk_len, out);
}

// Round 16
// 32.085 us; speedup vs baseline: 1.5113x; 1.5113x over previous
//
#include <hip/hip_runtime.h>
#include <hip/hip_bf16.h>

// ConditionalDense: out[b,u] = sum_d x[b,d]*kernel[cls[b],d,u] + bias[cls[b],u]
// B=2048, D=512, U=512, C=100, all float32.
// R16 = R14 geometry exactly (S=32, TU=128, 8 KB W pieces ring-4, bf16 xsb,
// ~404 blocks, 2 blk/CU) with a BARRIER-FREE main loop: W slices are
// wave-private (wbuf[ring][wave][16][32] f32; wave stages + reads only its
// own 32 u-cols) so no cross-wave LDS hazard exists -> waves self-pace on
// per-wave counted vmcnt and desynchronize (continuous DMA demand, no
// lockstep drain). Bank conflicts killed by both-sides XOR swizzle
// (source chunk cc ^ row&7; 2-way residual = free). R15's failure
// (4 KB granule + linear-LDS 4-way conflicts) reverted.

typedef __attribute__((ext_vector_type(8))) short bf16x8;
typedef __attribute__((ext_vector_type(4))) short short4v;
typedef __attribute__((ext_vector_type(4))) float floatx4;

constexpr int C_CLS   = 100;
constexpr int B_N     = 2048;
constexpr int D_DIM   = 512;
constexpr int U_DIM   = 512;
constexpr int S_CHUNK = 32;     // samples per chunk = 2 MFMA m-tiles
constexpr int MAX_CHUNKS = 164; // >= worst case (2048+100*31)/32 = 161
constexpr int TU      = 128;    // u-columns per block (wave owns 32)
constexpr int PROWS   = 16;     // d-rows per staged W piece
constexpr int PIECES  = D_DIM / PROWS;   // 32
constexpr int NQ      = 4;      // W ring depth (3 pieces in flight/wave)
constexpr int NWG     = 4 * MAX_CHUNKS;  // 656 = 8*82

__device__ __forceinline__ short f2bf(float f) {
    return (short)__builtin_bit_cast(unsigned short, __float2bfloat16(f));
}

// ---------------- fused sort kernel (single block, 1024 threads) ----------------

__global__ void k_sort(const int* __restrict__ cls, int* __restrict__ order,
                       int* __restrict__ total_chunks, int* __restrict__ chunk_cls,
                       int* __restrict__ chunk_start, int* __restrict__ chunk_len) {
    __shared__ int s_cnt[128], s_off[128], s_chk[128], s_cur[128], s_base[128];
    int tid = threadIdx.x;
    if (tid < 128) s_cnt[tid] = 0;
    __syncthreads();
    for (int i = tid; i < B_N; i += 1024) atomicAdd(&s_cnt[cls[i]], 1);
    __syncthreads();
    int cnt = 0, nch = 0;
    if (tid < 128) {
        cnt = (tid < C_CLS) ? s_cnt[tid] : 0;
        nch = (cnt + S_CHUNK - 1) / S_CHUNK;
        s_off[tid] = cnt; s_chk[tid] = nch;
    }
    __syncthreads();
    for (int st = 1; st < 128; st <<= 1) {   // Hillis-Steele inclusive scan
        int a = 0, b = 0;
        if (tid >= st && tid < 128) { a = s_off[tid - st]; b = s_chk[tid - st]; }
        __syncthreads();
        if (tid < 128) { s_off[tid] += a; s_chk[tid] += b; }
        __syncthreads();
    }
    if (tid < C_CLS) {
        int off = s_off[tid] - cnt;   // exclusive prefix of counts
        int cb  = s_chk[tid] - nch;   // exclusive prefix of chunk counts
        s_base[tid] = off;
        s_cur[tid]  = 0;
        for (int j = 0; j < nch; ++j) {
            chunk_cls[cb + j]   = tid;
            chunk_start[cb + j] = off + j * S_CHUNK;
            chunk_len[cb + j]   = min(S_CHUNK, cnt - j * S_CHUNK);
        }
    }
    if (tid == 127) *total_chunks = s_chk[127];
    __syncthreads();
    for (int i = tid; i < B_N; i += 1024) {
        int c = cls[i];
        int p = atomicAdd(&s_cur[c], 1);
        order[s_base[c] + p] = i;
    }
}

// ---------------- main kernel ----------------
// Block = (chunk, ytile): 32 samples x 128 u x full D=512. 256 thr/4 waves.
// Wave wv owns u [wv*32, wv*32+32) = 2 n-tiles x 2 m-tiles (4 MFMA/piece).
// Wave-private W slice per piece: [16 rows][32 cols] f32 = 2 KB, staged by
// 2 global_load_lds instrs (8 rows each; lane l -> row 8j+(l>>3), source
// 16-B chunk (l&7)^(row&7)). Read back with the same XOR.

#define ISSUE(pi, qq) do {                                                    \
    const int db_ = (pi) * PROWS;                                             \
    _Pragma("unroll")                                                         \
    for (int j_ = 0; j_ < 2; ++j_) {                                          \
        const int row_ = 8 * j_ + (lane >> 3);          /* 0..15 */           \
        const int sc_  = ((lane & 7) ^ (row_ & 7)) << 2; /* src f32 col */    \
        const float* gp_ = Wu + (size_t)(db_ + row_) * U_DIM + sc_;           \
        __builtin_amdgcn_global_load_lds(                                     \
            (const __attribute__((address_space(1))) void*)gp_,               \
            (__attribute__((address_space(3))) void*)&wbuf[qq][wv][8 * j_][0],\
            16, 0, 0);                                                        \
    }                                                                         \
} while (0)

#define COMPUTE(pi, qq) do {                                                  \
    bf16x8 a8_0, a8_1;                                                        \
    {                                                                         \
        const int xb_ = ((pi) * 32 + g4 * 8) ^ sxw_;                          \
        short4v a4 = *reinterpret_cast<const short4v*>(                       \
            (const char*)xsb + sA * 1024 + xb_);                              \
        a8_0[0]=a4[0]; a8_0[1]=a4[1]; a8_0[2]=a4[2]; a8_0[3]=a4[3];           \
        a8_0[4]=a4[0]; a8_0[5]=a4[1]; a8_0[6]=a4[2]; a8_0[7]=a4[3];           \
        short4v a4b = *reinterpret_cast<const short4v*>(                      \
            (const char*)xsb + (16 + sA) * 1024 + xb_);                       \
        a8_1[0]=a4b[0]; a8_1[1]=a4b[1]; a8_1[2]=a4b[2]; a8_1[3]=a4b[3];       \
        a8_1[4]=a4b[0]; a8_1[5]=a4b[1]; a8_1[6]=a4b[2]; a8_1[7]=a4b[3];       \
    }                                                                         \
    const char* wb_ = (const char*)&wbuf[qq][wv][0][0];                       \
    _Pragma("unroll")                                                         \
    for (int nt = 0; nt < 2; ++nt) {                                          \
        const int c_  = nt * 16 + sA;             /* col 0..31 in slice */    \
        bf16x8 b8;                                                            \
        _Pragma("unroll")                                                     \
        for (int j_ = 0; j_ < 4; ++j_) {                                      \
            const int rl_ = g4 * 4 + j_;                                      \
            const int cc_ = ((c_ >> 2) ^ (rl_ & 7));                          \
            float w_ = *reinterpret_cast<const float*>(                       \
                wb_ + rl_ * 128 + cc_ * 16 + (c_ & 3) * 4);                   \
            b8[j_] = f2bf(w_);                                                \
        }                                                                     \
        b8[4] = 0; b8[5] = 0; b8[6] = 0; b8[7] = 0;                           \
        acc0[nt] = __builtin_amdgcn_mfma_f32_16x16x32_bf16(a8_0, b8, acc0[nt], 0, 0, 0); \
        acc1[nt] = __builtin_amdgcn_mfma_f32_16x16x32_bf16(a8_1, b8, acc1[nt], 0, 0, 0); \
    }                                                                         \
} while (0)

// Barrier-free step: per-wave wait (NCNT instrs may stay outstanding),
// compute, drain own ds_reads, refill own slot with piece pi+4.
#define STEP(pi, NCNT) do {                                                   \
    asm volatile("s_waitcnt vmcnt(" #NCNT ")" ::: "memory");                  \
    COMPUTE(pi, (pi) & 3);                                                    \
    asm volatile("s_waitcnt lgkmcnt(0)" ::: "memory");                        \
    if ((pi) + NQ < PIECES) ISSUE((pi) + NQ, (pi) & 3);                       \
} while (0)

__launch_bounds__(256, 2)
__global__ void k_main(const float* __restrict__ x, const float* __restrict__ kern,
                       const float* __restrict__ bias, const int* __restrict__ order,
                       const int* __restrict__ total_chunks,
                       const int* __restrict__ chunk_cls,
                       const int* __restrict__ chunk_start,
                       const int* __restrict__ chunk_len,
                       float* __restrict__ out) {
    // Runtime-balanced bijective XCD swizzle over active count A = 4*tc.
    int tc = *total_chunks;
    int A  = 4 * tc;
    int xc = blockIdx.x & 7;
    int ii = blockIdx.x >> 3;
    int q  = A >> 3, r = A & 7;
    int mycnt = (xc < r) ? (q + 1) : q;
    if (ii >= mycnt) return;            // block-uniform exit (before barriers)
    int g = ((xc < r) ? xc * (q + 1) : r * (q + 1) + (xc - r) * q) + ii;

    int chunk = g >> 2;
    int ytile = g & 3;

    int tid  = threadIdx.x;
    int lane = tid & 63;
    int wv   = tid >> 6;
    int sA   = lane & 15;
    int g4   = lane >> 4;
    const int sxw_ = (sA & 7) << 4;     // xsb row-XOR (rows sA and 16+sA share it)

    int c     = chunk_cls[chunk];
    int start = chunk_start[chunk];
    int len   = chunk_len[chunk];
    int u0    = ytile * TU;

    __shared__ float          wbuf[NQ][4][PROWS][32]; // 32 KB, ring-4, wave-private
    __shared__ unsigned short xsb[S_CHUNK][D_DIM];    // 32 KB bf16, swizzled
    __shared__ int            sidx[S_CHUNK];          // -> 64.4 KB, 2 blk/CU

    const float* Wu = kern + (size_t)c * (D_DIM * U_DIM) + u0 + wv * 32;

    // ---- prologue ----
    if (tid < S_CHUNK) sidx[tid] = (tid < len) ? order[start + tid] : -1;
    asm volatile("s_waitcnt lgkmcnt(0)" ::: "memory");
    __builtin_amdgcn_s_barrier();          // sidx visible

    // x: 2 passes; pass p: thread handles row p*16 + (tid>>4), 32 cols.
    float4 xv0[8], xv1[8];
    int srow0 = (tid >> 4), srow1 = 16 + (tid >> 4);
    int cb    = (tid & 15) * 32;
    {
        int b0 = sidx[srow0]; if (b0 < 0) b0 = sidx[0];
        int b1 = sidx[srow1]; if (b1 < 0) b1 = sidx[0];
        #pragma unroll
        for (int j = 0; j < 8; ++j)
            xv0[j] = reinterpret_cast<const float4*>(x + (size_t)b0 * D_DIM + cb)[j];
        #pragma unroll
        for (int j = 0; j < 8; ++j)
            xv1[j] = reinterpret_cast<const float4*>(x + (size_t)b1 * D_DIM + cb)[j];
    }
    ISSUE(0, 0);                           // W pieces 0..3 (2 instrs/wave each)
    ISSUE(1, 1);
    ISSUE(2, 2);
    ISSUE(3, 3);
    asm volatile("s_waitcnt vmcnt(8)" ::: "memory");   // x's 16 done; W's 8 fly

    {   // convert f32 -> bf16, write swizzled 16-B chunks
        #pragma unroll
        for (int p = 0; p < 2; ++p) {
            int   row  = p ? srow1 : srow0;
            char* xrow = (char*)xsb + row * 1024;
            int   swz  = (row & 7) << 4;
            #pragma unroll
            for (int m = 0; m < 4; ++m) {
                float4 va = p ? xv1[2*m]     : xv0[2*m];
                float4 vb = p ? xv1[2*m + 1] : xv0[2*m + 1];
                bf16x8 pk;
                pk[0] = f2bf(va.x); pk[1] = f2bf(va.y);
                pk[2] = f2bf(va.z); pk[3] = f2bf(va.w);
                pk[4] = f2bf(vb.x); pk[5] = f2bf(vb.y);
                pk[6] = f2bf(vb.z); pk[7] = f2bf(vb.w);
                *reinterpret_cast<bf16x8*>(xrow + ((cb * 2 + m * 16) ^ swz)) = pk;
            }
        }
    }
    asm volatile("s_waitcnt lgkmcnt(0)" ::: "memory");
    __builtin_amdgcn_s_barrier();          // xsb visible — LAST barrier

    floatx4 acc0[2], acc1[2];
    #pragma unroll
    for (int k = 0; k < 2; ++k) {
        acc0[k] = (floatx4){0.f, 0.f, 0.f, 0.f};
        acc1[k] = (floatx4){0.f, 0.f, 0.f, 0.f};
    }

    // ---- main loop: 32 pieces, ring-4, barrier-free, per-wave vmcnt.
    // Steady: wait vmcnt(6) = pieces i+1..i+3 (2 instrs each) outstanding.
    #pragma unroll 1
    for (int i = 0; i <= 27; ++i) STEP(i, 6);
    STEP(28, 6);
    STEP(29, 4);
    STEP(30, 2);
    STEP(31, 0);

    // ---- epilogue: direct stores, one writer per output element ----
    #pragma unroll
    for (int mt = 0; mt < 2; ++mt) {
        #pragma unroll
        for (int nt = 0; nt < 2; ++nt) {
            int u  = u0 + (wv << 5) + nt * 16 + sA;
            float bb = bias[c * U_DIM + u];
            floatx4 a = mt ? acc1[nt] : acc0[nt];
            #pragma unroll
            for (int r2 = 0; r2 < 4; ++r2) {
                int b = sidx[mt * 16 + g4 * 4 + r2];
                if (b >= 0) out[(size_t)b * U_DIM + u] = a[r2] + bb;
            }
        }
    }
}

// ---------------- launch ----------------

extern "C" void kernel_launch(void* const* d_in, const int* in_sizes, int n_in,
                              void* d_out, int out_size, void* d_ws, size_t ws_size,
                              hipStream_t stream) {
    const float* x    = (const float*)d_in[0];
    const int*   cls  = (const int*)d_in[1];
    const float* kern = (const float*)d_in[2];
    const float* bias = (const float*)d_in[3];
    float*       out  = (float*)d_out;

    int* ws           = (int*)d_ws;
    int* order        = ws;          // 2048
    int* total_chunks = ws + 2048;   // 1
    int* chunk_cls    = ws + 2112;   // 164
    int* chunk_start  = ws + 2304;   // 164
    int* chunk_len    = ws + 2496;   // 164

    hipLaunchKernelGGL(k_sort, dim3(1), dim3(1024), 0, stream,
                       cls, order, total_chunks, chunk_cls, chunk_start, chunk_len);
    hipLaunchKernelGGL(k_main, dim3(NWG), dim3(256), 0, stream,
                       x, kern, bias, order, total_chunks, chunk_cls, chunk_start, chunk_len, out);
}